// Round 5
// baseline (273.605 us; speedup 1.0000x reference)
//
#include <hip/hip_runtime.h>

// HeaNet R23 = R22 with the gaussian-constant fix: __expf(x) already computes
// e^x (HIP folds log2e into v_exp_f32 internally); R22 pre-multiplied by
// log2e, making every table gaussian exp(1.4427*COEFF*d^2) -> absmax 172K.
// Structure (from R22): tabulate the per-edge filter MLP. W_l(ew) depends on
// ONE scalar; gaussians underflow past ew~12 so W is constant beyond 12.5.
// Build a 2048-knot table over [0,12.8] per layer (f32 math, f16 storage) in
// setup; edge kernel lerps: per (edge, layer) = 3 dword loads + ~10 VALU.
// No MFMA, no LDS GEMM tiles, no per-edge transcendentals, one launch for
// all 6 layers.

#define NNODES 8192
#define NGRAPH 32
#define NELEM  5
#define NEDGE  131072
#define HD     128
#define FD     128
#define GD     50
#define LL     6
#define NC     160
#define NZ     100
#define CUT    10.0f
#define LOG2_  0.69314718055994531f

#define CAP    1024               // per-cid slot capacity
#define PADE   (NC * CAP)         // 163840
#define PADG   (PADE / 64)        // 2560 groups
#define CSTR   16                 // cursor stride in ints (64B cacheline)

#define NK     2048               // table knots per layer
#define TI     32                 // knots built per block
#define HSTEP  0.00625f           // 12.8 / 2048
#define INVH   160.0f
#define DELTA  (10.0f / 49.0f)
#define COEFF  (-12.005f)         // -0.5/DELTA^2 = -0.5*(49/10)^2 exact

#define NSCATB (NEDGE / 256)      // 512
#define NXHZB  (LL * NZ / 2)      // 300
#define NTABB  (LL * (NK / TI))   // 384

typedef _Float16 h2 __attribute__((ext_vector_type(2)));

__device__ __forceinline__ float ssp(float x) {         // softplus(x) - ln2, stable
    float m = fmaxf(x, 0.0f);
    float zz = __expf(-fabsf(x));
    return m + __logf(1.0f + zz) - LOG2_;
}

// ---------- K1: scatter + counts + xh16 + filter table (independent blocks) ----------
__global__ __launch_bounds__(256) void setup_kernel(
    const float* __restrict__ pos, const int* __restrict__ ei,
    const int* __restrict__ comp_id, const int* __restrict__ z,
    const float* __restrict__ w1, const float* __restrict__ b1in,
    const float* __restrict__ w2, const float* __restrict__ b2in,
    const float* __restrict__ emb, const float* __restrict__ cf1,
    int* __restrict__ counts, int* __restrict__ cursor,
    float* __restrict__ ew_s, float* __restrict__ c_s, int* __restrict__ zsrc_s,
    _Float16* __restrict__ xh16, _Float16* __restrict__ tab)
{
    __shared__ float Gl[TI][52];     // gaussian features for TI knots
    __shared__ float Sl[TI][FD];     // ssp(T) for TI knots
    int bx = blockIdx.x;
    int tid = threadIdx.x;
    if (bx < NSCATB) {
        int e = bx * 256 + tid;
        int s = ei[e], d = ei[NEDGE + e];
        float dx = pos[3*s]   - pos[3*d];
        float dy = pos[3*s+1] - pos[3*d+1];
        float dz = pos[3*s+2] - pos[3*d+2];
        float d2 = dx*dx + dy*dy + dz*dz;
        float ew = sqrtf(d2);
        float C  = CUT / (1e-10f + d2) - 1.0f;
        int cid = comp_id[d];
        int idx = cid * CAP + atomicAdd(&cursor[cid * CSTR], 1);
        ew_s[idx] = ew; c_s[idx] = C; zsrc_s[idx] = z[s];
        if (e < NNODES) atomicAdd(&counts[comp_id[e]], 1);
        return;
    }
    int bz = bx - NSCATB;
    if (bz < NXHZB) {
        // xh16[l][zv][f] = (emb[zv] @ cf1_l)[f], f16 plain layout
        int l = bz / (NZ / 2);
        int zv = (bz % (NZ / 2)) * 2 + (tid >> 7);
        int f = tid & 127;
        const float* h = emb + zv * HD;
        const float* w = cf1 + l * HD * FD;
        float acc = 0.0f;
        #pragma unroll 8
        for (int k = 0; k < HD; ++k) acc = fmaf(h[k], w[k * FD + f], acc);
        xh16[(l * NZ + zv) * FD + f] = (_Float16)acc;
        return;
    }
    // ---- table build: W_l(ew_i) for TI knots, all-f32 math ----
    int bt = bz - NXHZB;                  // 0..383
    int l  = bt >> 6;                     // NK/TI = 64
    int i0 = (bt & 63) * TI;
    // phase A: gaussians, TI*GD entries.  __expf(x) == e^x (log2e folded by HW path)
    for (int idx = tid; idx < TI * GD; idx += 256) {
        int il = idx / GD, k = idx - il * GD;
        float d = (float)(i0 + il) * HSTEP - (float)k * DELTA;
        Gl[il][k] = __expf(COEFF * d * d);
    }
    __syncthreads();
    // phase B: T = G@W1 + b1 ; S = ssp(T)
    {
        int f = tid & 127;
        float b1v = b1in[l * FD + f];
        #pragma unroll 1
        for (int it = 0; it < TI / 2; ++it) {
            int il = (tid >> 7) + it * 2;
            float t = b1v;
            #pragma unroll 10
            for (int k = 0; k < GD; ++k)
                t = fmaf(Gl[il][k], w1[(l * GD + k) * FD + f], t);
            Sl[il][f] = ssp(t);
        }
    }
    __syncthreads();
    // phase C: W = S@W2 + b2 -> f16 table
    {
        int f = tid & 127;
        float b2v = b2in[l * FD + f];
        #pragma unroll 1
        for (int it = 0; it < TI / 2; ++it) {
            int il = (tid >> 7) + it * 2;
            float wv = b2v;
            #pragma unroll 8
            for (int k = 0; k < FD; ++k)
                wv = fmaf(Sl[il][k], w2[(l * FD + k) * FD + f], wv);
            tab[((size_t)(l * NK + i0 + il)) * FD + f] = (_Float16)wv;
        }
    }
}

// ---------- K2 (hot): 64 edges/block, all 6 layers, table lerp ----------
// grid = PADG, g-major: cid = bx % NC -> dummy groups cluster at tail.
__global__ __launch_bounds__(256, 8) void edge_kernel(
    const float* __restrict__ ew_s, const float* __restrict__ c_s,
    const int* __restrict__ zsrc_s,
    const _Float16* __restrict__ tab, const _Float16* __restrict__ xh16,
    float* __restrict__ comp_acc)
{
    __shared__ int4 meta[64];     // {ib_byte, frac_bits, C_bits, xh_byte}

    const int tid  = threadIdx.x;
    const int lane = tid & 63;
    const int fq   = tid >> 6;
    const int cid  = blockIdx.x % NC;
    const int gg   = blockIdx.x / NC;
    const int g0   = cid * CAP + gg * 64;

    const float ce = c_s[g0 + lane];
    if (__all(ce == 0.0f)) return;                 // fully-dummy group

    if (tid < 64) {
        float ew = ew_s[g0 + tid];
        int zz   = zsrc_s[g0 + tid];
        float fi = ew * INVH;
        int i = (int)fi; if (i > NK - 2) i = NK - 2;
        float fr = fi - (float)i; if (fr > 1.0f) fr = 1.0f;
        meta[tid] = make_int4(i * (FD * 2), __float_as_int(fr),
                              __float_as_int(c_s[g0 + tid]), zz * (FD * 2));
    }
    __syncthreads();

    float acc[LL][2];
    #pragma unroll
    for (int l = 0; l < LL; ++l) { acc[l][0] = 0.0f; acc[l][1] = 0.0f; }

    const int lane4 = lane * 4;
    for (int k = 0; k < 16; ++k) {
        int4 m = meta[fq * 16 + k];
        const int   ib = __builtin_amdgcn_readfirstlane(m.x);
        const float fr = __int_as_float(__builtin_amdgcn_readfirstlane(m.y));
        const float C  = __int_as_float(__builtin_amdgcn_readfirstlane(m.z));
        const int   xo = __builtin_amdgcn_readfirstlane(m.w);
        const _Float16 frh = (_Float16)fr;
        const h2 fr2 = {frh, frh};
        #pragma unroll
        for (int l = 0; l < LL; ++l) {
            const char* tp = (const char*)tab  + (size_t)l * (NK * FD * 2) + ib;
            const char* xp = (const char*)xh16 + (size_t)l * (NZ * FD * 2) + xo;
            unsigned ua = *(const unsigned*)(tp + lane4);            // row i
            unsigned ub = *(const unsigned*)(tp + lane4 + FD * 2);   // row i+1
            unsigned ux = *(const unsigned*)(xp + lane4);
            h2 a2 = __builtin_bit_cast(h2, ua);
            h2 b2 = __builtin_bit_cast(h2, ub);
            h2 x2 = __builtin_bit_cast(h2, ux);
            h2 w2v = fr2 * (b2 - a2) + a2;                           // lerp (pk f16)
            float x0 = (float)x2[0], x1 = (float)x2[1];
            acc[l][0] = fmaf((float)w2v[0], C * x0, acc[l][0]);
            acc[l][1] = fmaf((float)w2v[1], C * x1, acc[l][1]);
        }
    }

    float* cacc = comp_acc + cid * FD + lane * 2;
    #pragma unroll
    for (int l = 0; l < LL; ++l) {
        atomicAdd(&cacc[l * NC * FD],     acc[l][0]);
        atomicAdd(&cacc[l * NC * FD + 1], acc[l][1]);
    }
}

// ---------- K3: per-component update ((NC,LL) = 960 blocks) ----------
__global__ __launch_bounds__(128) void comp_kernel(
    const float* __restrict__ comp_acc, const int* __restrict__ counts,
    const float* __restrict__ cf2w, const float* __restrict__ cf2b,
    const float* __restrict__ intw, const float* __restrict__ intb,
    float* __restrict__ types_acc)
{
    int c = blockIdx.x, l = blockIdx.y, f = threadIdx.x;
    __shared__ float comp[FD];
    __shared__ float sx[FD];
    comp[f] = comp_acc[(l * NC + c) * FD + f] / (float)counts[c];
    __syncthreads();
    float acc = cf2b[l * HD + f];
    const float* w = cf2w + l * FD * HD;
    #pragma unroll 8
    for (int k = 0; k < FD; ++k) acc = fmaf(comp[k], w[k * HD + f], acc);
    sx[f] = ssp(acc);
    __syncthreads();
    float acc2 = intb[l * HD + f];
    const float* wi = intw + l * HD * HD;
    #pragma unroll 8
    for (int k = 0; k < HD; ++k) acc2 = fmaf(sx[k], wi[k * HD + f], acc2);
    atomicAdd(&types_acc[c * HD + f], acc2);
}

// ---------- K4: readout ----------
__global__ __launch_bounds__(64) void readout_kernel(
    const float* __restrict__ types_acc, const float* __restrict__ emb,
    const int* __restrict__ comps_z,
    const float* __restrict__ w1, const float* __restrict__ b1,
    const float* __restrict__ w2, const float* __restrict__ b2,
    float* __restrict__ out)
{
    int b = blockIdx.x, lane = threadIdx.x;
    float sum = 0.0f;
    for (int cc = 0; cc < NELEM; ++cc) {
        int c = b * NELEM + cc;
        int zc = comps_z[c];
        float acc = b1[lane];
        const float* ta = types_acc + c * HD;
        const float* eb = emb + zc * HD;
        #pragma unroll 8
        for (int k = 0; k < HD; ++k) acc = fmaf(ta[k] + eb[k], w1[k * 64 + lane], acc);
        sum += ssp(acc) * w2[lane];
    }
    #pragma unroll
    for (int s = 32; s > 0; s >>= 1) sum += __shfl_xor(sum, s);
    if (lane == 0) out[b] = sum + (float)NELEM * b2[0];
}

extern "C" void kernel_launch(void* const* d_in, const int* in_sizes, int n_in,
                              void* d_out, int out_size, void* d_ws, size_t ws_size,
                              hipStream_t stream) {
    (void)in_sizes; (void)n_in; (void)out_size; (void)ws_size;
    const float* pos     = (const float*)d_in[0];
    const float* emb     = (const float*)d_in[1];
    const float* mlp_w1  = (const float*)d_in[2];
    const float* mlp_b1  = (const float*)d_in[3];
    const float* mlp_w2  = (const float*)d_in[4];
    const float* mlp_b2  = (const float*)d_in[5];
    const float* cf1     = (const float*)d_in[6];
    const float* cf2w    = (const float*)d_in[7];
    const float* cf2b    = (const float*)d_in[8];
    const float* intw    = (const float*)d_in[9];
    const float* intb    = (const float*)d_in[10];
    const float* ow1     = (const float*)d_in[11];
    const float* ob1     = (const float*)d_in[12];
    const float* ow2     = (const float*)d_in[13];
    const float* ob2     = (const float*)d_in[14];
    const int*   z       = (const int*)d_in[15];
    const int*   comp_id = (const int*)d_in[16];
    const int*   ei      = (const int*)d_in[17];
    const int*   comps_z = (const int*)d_in[18];
    float* out = (float*)d_out;

    char* ws = (char*)d_ws;
    size_t off = 0;
    auto alloc = [&](size_t bytes) -> void* {
        void* p = ws + off;
        off += (bytes + 255) & ~(size_t)255;
        return p;
    };
    // zeroed prefix: comp_acc | counts | types_acc | cursor | c_s | zsrc_s | ew_s
    float* comp_acc  = (float*)alloc((size_t)LL * NC * FD * 4);
    int*   counts    = (int*)  alloc(NC * 4);
    float* types_acc = (float*)alloc((size_t)NC * HD * 4);
    int*   cursor    = (int*)  alloc(NC * CSTR * 4);
    float* c_s       = (float*)alloc((size_t)PADE * 4);
    int*   zsrc_s    = (int*)  alloc((size_t)PADE * 4);
    float* ew_s      = (float*)alloc((size_t)PADE * 4);   // zeroed: dummy rows exact-0
    size_t zero_bytes = off;
    _Float16* xh16 = (_Float16*)alloc((size_t)LL * NZ * FD * 2);
    _Float16* tab  = (_Float16*)alloc((size_t)LL * NK * FD * 2);

    (void)hipMemsetAsync(d_ws, 0, zero_bytes, stream);

    setup_kernel<<<NSCATB + NXHZB + NTABB, 256, 0, stream>>>(
        pos, ei, comp_id, z, mlp_w1, mlp_b1, mlp_w2, mlp_b2, emb, cf1,
        counts, cursor, ew_s, c_s, zsrc_s, xh16, tab);
    edge_kernel <<<PADG, 256, 0, stream>>>(ew_s, c_s, zsrc_s, tab, xh16, comp_acc);
    comp_kernel <<<dim3(NC, LL), 128, 0, stream>>>(comp_acc, counts, cf2w, cf2b,
                                                   intw, intb, types_acc);
    readout_kernel<<<NGRAPH, 64, 0, stream>>>(types_acc, emb, comps_z,
                                              ow1, ob1, ow2, ob2, out);
}

// Round 6
// 221.257 us; speedup vs baseline: 1.2366x; 1.2366x over previous
//
#include <hip/hip_runtime.h>

// HeaNet R24 = R23 with the table build re-tiled (the 100.7us long pole).
// R23 post-mortem: table section ran as 384 blocks (1.5/CU, machine ~idle)
// with one global weight load per fmaf (latency-bound, VALUBusy 29%).
// R24: KNB=16 knots/block -> 768 blocks (3/CU), k-outer register reuse:
// each weight element loaded ONCE per thread and applied to 8 knot
// accumulators; G/S rows read from LDS as same-address broadcast float4
// (conflict-free). ~1.4 instr/fma vs latency-serial. Everything else
// (scatter, xh16, edge lerp kernel, comp, readout) identical to R23.

#define NNODES 8192
#define NGRAPH 32
#define NELEM  5
#define NEDGE  131072
#define HD     128
#define FD     128
#define GD     50
#define LL     6
#define NC     160
#define NZ     100
#define CUT    10.0f
#define LOG2_  0.69314718055994531f

#define CAP    1024               // per-cid slot capacity
#define PADE   (NC * CAP)         // 163840
#define PADG   (PADE / 64)        // 2560 groups
#define CSTR   16                 // cursor stride in ints (64B cacheline)

#define NK     2048               // table knots per layer
#define KNB    16                 // knots built per block
#define HSTEP  0.00625f           // 12.8 / 2048
#define INVH   160.0f
#define DELTA  (10.0f / 49.0f)
#define COEFF  (-12.005f)         // -0.5/DELTA^2 = -0.5*(49/10)^2 exact

#define NSCATB (NEDGE / 256)      // 512
#define NXHZB  (LL * NZ / 2)      // 300
#define NTABB  (LL * (NK / KNB))  // 768

typedef _Float16 h2 __attribute__((ext_vector_type(2)));

__device__ __forceinline__ float ssp(float x) {         // softplus(x) - ln2, stable
    float m = fmaxf(x, 0.0f);
    float zz = __expf(-fabsf(x));
    return m + __logf(1.0f + zz) - LOG2_;
}

// ---------- K1: scatter + counts + xh16 + filter table (independent blocks) ----------
__global__ __launch_bounds__(256) void setup_kernel(
    const float* __restrict__ pos, const int* __restrict__ ei,
    const int* __restrict__ comp_id, const int* __restrict__ z,
    const float* __restrict__ w1, const float* __restrict__ b1in,
    const float* __restrict__ w2, const float* __restrict__ b2in,
    const float* __restrict__ emb, const float* __restrict__ cf1,
    int* __restrict__ counts, int* __restrict__ cursor,
    float* __restrict__ ew_s, float* __restrict__ c_s, int* __restrict__ zsrc_s,
    _Float16* __restrict__ xh16, _Float16* __restrict__ tab)
{
    __shared__ __align__(16) float Gt[KNB][52];   // gaussians (pitch 52: 16B-aligned rows)
    __shared__ __align__(16) float St[KNB][FD];   // ssp(T)
    int bx = blockIdx.x;
    int tid = threadIdx.x;
    if (bx < NSCATB) {
        int e = bx * 256 + tid;
        int s = ei[e], d = ei[NEDGE + e];
        float dx = pos[3*s]   - pos[3*d];
        float dy = pos[3*s+1] - pos[3*d+1];
        float dz = pos[3*s+2] - pos[3*d+2];
        float d2 = dx*dx + dy*dy + dz*dz;
        float ew = sqrtf(d2);
        float C  = CUT / (1e-10f + d2) - 1.0f;
        int cid = comp_id[d];
        int idx = cid * CAP + atomicAdd(&cursor[cid * CSTR], 1);
        ew_s[idx] = ew; c_s[idx] = C; zsrc_s[idx] = z[s];
        if (e < NNODES) atomicAdd(&counts[comp_id[e]], 1);
        return;
    }
    int bz = bx - NSCATB;
    if (bz < NXHZB) {
        // xh16[l][zv][f] = (emb[zv] @ cf1_l)[f], f16 plain layout
        int l = bz / (NZ / 2);
        int zv = (bz % (NZ / 2)) * 2 + (tid >> 7);
        int f = tid & 127;
        const float* h = emb + zv * HD;
        const float* w = cf1 + l * HD * FD;
        float acc = 0.0f;
        #pragma unroll 8
        for (int k = 0; k < HD; ++k) acc = fmaf(h[k], w[k * FD + f], acc);
        xh16[(l * NZ + zv) * FD + f] = (_Float16)acc;
        return;
    }
    // ---- table build: W_l(ew_i) for KNB knots, k-outer register reuse ----
    int bt = bz - NXHZB;                  // 0..767
    int l  = bt >> 7;                     // NK/KNB = 128 blocks per layer
    int i0 = (bt & 127) * KNB;
    const int f    = tid & 127;
    const int half = tid >> 7;            // 0/1: knots il = half + 2*j

    // phase A: gaussians (800 entries, ~3 exps/thread)
    for (int idx = tid; idx < KNB * GD; idx += 256) {
        int il = idx / GD, k = idx - il * GD;
        float d = (float)(i0 + il) * HSTEP - (float)k * DELTA;
        Gt[il][k] = __expf(COEFF * d * d);
    }
    __syncthreads();

    // phase B: T = G@W1 + b1 ; S = ssp(T).  8 accumulators/thread.
    {
        const float* w1l = w1 + (size_t)l * GD * FD + f;
        float b1v = b1in[l * FD + f];
        float t[8];
        #pragma unroll
        for (int j = 0; j < 8; ++j) t[j] = b1v;
        #pragma unroll 2
        for (int kk = 0; kk < 12; ++kk) {            // k = 0..47
            int k = kk * 4;
            float wv0 = w1l[(size_t)(k + 0) * FD];
            float wv1 = w1l[(size_t)(k + 1) * FD];
            float wv2 = w1l[(size_t)(k + 2) * FD];
            float wv3 = w1l[(size_t)(k + 3) * FD];
            #pragma unroll
            for (int j = 0; j < 8; ++j) {
                const float4 g = *(const float4*)&Gt[half + 2 * j][k];  // broadcast
                t[j] = fmaf(g.x, wv0, t[j]);
                t[j] = fmaf(g.y, wv1, t[j]);
                t[j] = fmaf(g.z, wv2, t[j]);
                t[j] = fmaf(g.w, wv3, t[j]);
            }
        }
        #pragma unroll
        for (int k = 48; k < 50; ++k) {              // tail
            float wv = w1l[(size_t)k * FD];
            #pragma unroll
            for (int j = 0; j < 8; ++j) t[j] = fmaf(Gt[half + 2 * j][k], wv, t[j]);
        }
        #pragma unroll
        for (int j = 0; j < 8; ++j) St[half + 2 * j][f] = ssp(t[j]);
    }
    __syncthreads();

    // phase C: W = S@W2 + b2 -> f16 table.  8 accumulators/thread.
    {
        const float* w2l = w2 + (size_t)l * FD * FD + f;
        float b2v = b2in[l * FD + f];
        float wa[8];
        #pragma unroll
        for (int j = 0; j < 8; ++j) wa[j] = b2v;
        #pragma unroll 2
        for (int kk = 0; kk < 32; ++kk) {            // k = 0..127
            int k = kk * 4;
            float wv0 = w2l[(size_t)(k + 0) * FD];
            float wv1 = w2l[(size_t)(k + 1) * FD];
            float wv2 = w2l[(size_t)(k + 2) * FD];
            float wv3 = w2l[(size_t)(k + 3) * FD];
            #pragma unroll
            for (int j = 0; j < 8; ++j) {
                const float4 s = *(const float4*)&St[half + 2 * j][k];  // broadcast
                wa[j] = fmaf(s.x, wv0, wa[j]);
                wa[j] = fmaf(s.y, wv1, wa[j]);
                wa[j] = fmaf(s.z, wv2, wa[j]);
                wa[j] = fmaf(s.w, wv3, wa[j]);
            }
        }
        #pragma unroll
        for (int j = 0; j < 8; ++j)
            tab[((size_t)(l * NK + i0 + half + 2 * j)) * FD + f] = (_Float16)wa[j];
    }
}

// ---------- K2 (hot): 64 edges/block, all 6 layers, table lerp ----------
// grid = PADG, g-major: cid = bx % NC -> dummy groups cluster at tail.
__global__ __launch_bounds__(256, 8) void edge_kernel(
    const float* __restrict__ ew_s, const float* __restrict__ c_s,
    const int* __restrict__ zsrc_s,
    const _Float16* __restrict__ tab, const _Float16* __restrict__ xh16,
    float* __restrict__ comp_acc)
{
    __shared__ int4 meta[64];     // {ib_byte, frac_bits, C_bits, xh_byte}

    const int tid  = threadIdx.x;
    const int lane = tid & 63;
    const int fq   = tid >> 6;
    const int cid  = blockIdx.x % NC;
    const int gg   = blockIdx.x / NC;
    const int g0   = cid * CAP + gg * 64;

    const float ce = c_s[g0 + lane];
    if (__all(ce == 0.0f)) return;                 // fully-dummy group

    if (tid < 64) {
        float ew = ew_s[g0 + tid];
        int zz   = zsrc_s[g0 + tid];
        float fi = ew * INVH;
        int i = (int)fi; if (i > NK - 2) i = NK - 2;
        float fr = fi - (float)i; if (fr > 1.0f) fr = 1.0f;
        meta[tid] = make_int4(i * (FD * 2), __float_as_int(fr),
                              __float_as_int(c_s[g0 + tid]), zz * (FD * 2));
    }
    __syncthreads();

    float acc[LL][2];
    #pragma unroll
    for (int l = 0; l < LL; ++l) { acc[l][0] = 0.0f; acc[l][1] = 0.0f; }

    const int lane4 = lane * 4;
    for (int k = 0; k < 16; ++k) {
        int4 m = meta[fq * 16 + k];
        const int   ib = __builtin_amdgcn_readfirstlane(m.x);
        const float fr = __int_as_float(__builtin_amdgcn_readfirstlane(m.y));
        const float C  = __int_as_float(__builtin_amdgcn_readfirstlane(m.z));
        const int   xo = __builtin_amdgcn_readfirstlane(m.w);
        const _Float16 frh = (_Float16)fr;
        const h2 fr2 = {frh, frh};
        #pragma unroll
        for (int l = 0; l < LL; ++l) {
            const char* tp = (const char*)tab  + (size_t)l * (NK * FD * 2) + ib;
            const char* xp = (const char*)xh16 + (size_t)l * (NZ * FD * 2) + xo;
            unsigned ua = *(const unsigned*)(tp + lane4);            // row i
            unsigned ub = *(const unsigned*)(tp + lane4 + FD * 2);   // row i+1
            unsigned ux = *(const unsigned*)(xp + lane4);
            h2 a2 = __builtin_bit_cast(h2, ua);
            h2 b2 = __builtin_bit_cast(h2, ub);
            h2 x2 = __builtin_bit_cast(h2, ux);
            h2 w2v = fr2 * (b2 - a2) + a2;                           // lerp (pk f16)
            float x0 = (float)x2[0], x1 = (float)x2[1];
            acc[l][0] = fmaf((float)w2v[0], C * x0, acc[l][0]);
            acc[l][1] = fmaf((float)w2v[1], C * x1, acc[l][1]);
        }
    }

    float* cacc = comp_acc + cid * FD + lane * 2;
    #pragma unroll
    for (int l = 0; l < LL; ++l) {
        atomicAdd(&cacc[l * NC * FD],     acc[l][0]);
        atomicAdd(&cacc[l * NC * FD + 1], acc[l][1]);
    }
}

// ---------- K3: per-component update ((NC,LL) = 960 blocks) ----------
__global__ __launch_bounds__(128) void comp_kernel(
    const float* __restrict__ comp_acc, const int* __restrict__ counts,
    const float* __restrict__ cf2w, const float* __restrict__ cf2b,
    const float* __restrict__ intw, const float* __restrict__ intb,
    float* __restrict__ types_acc)
{
    int c = blockIdx.x, l = blockIdx.y, f = threadIdx.x;
    __shared__ float comp[FD];
    __shared__ float sx[FD];
    comp[f] = comp_acc[(l * NC + c) * FD + f] / (float)counts[c];
    __syncthreads();
    float acc = cf2b[l * HD + f];
    const float* w = cf2w + l * FD * HD;
    #pragma unroll 8
    for (int k = 0; k < FD; ++k) acc = fmaf(comp[k], w[k * HD + f], acc);
    sx[f] = ssp(acc);
    __syncthreads();
    float acc2 = intb[l * HD + f];
    const float* wi = intw + l * HD * HD;
    #pragma unroll 8
    for (int k = 0; k < HD; ++k) acc2 = fmaf(sx[k], wi[k * HD + f], acc2);
    atomicAdd(&types_acc[c * HD + f], acc2);
}

// ---------- K4: readout ----------
__global__ __launch_bounds__(64) void readout_kernel(
    const float* __restrict__ types_acc, const float* __restrict__ emb,
    const int* __restrict__ comps_z,
    const float* __restrict__ w1, const float* __restrict__ b1,
    const float* __restrict__ w2, const float* __restrict__ b2,
    float* __restrict__ out)
{
    int b = blockIdx.x, lane = threadIdx.x;
    float sum = 0.0f;
    for (int cc = 0; cc < NELEM; ++cc) {
        int c = b * NELEM + cc;
        int zc = comps_z[c];
        float acc = b1[lane];
        const float* ta = types_acc + c * HD;
        const float* eb = emb + zc * HD;
        #pragma unroll 8
        for (int k = 0; k < HD; ++k) acc = fmaf(ta[k] + eb[k], w1[k * 64 + lane], acc);
        sum += ssp(acc) * w2[lane];
    }
    #pragma unroll
    for (int s = 32; s > 0; s >>= 1) sum += __shfl_xor(sum, s);
    if (lane == 0) out[b] = sum + (float)NELEM * b2[0];
}

extern "C" void kernel_launch(void* const* d_in, const int* in_sizes, int n_in,
                              void* d_out, int out_size, void* d_ws, size_t ws_size,
                              hipStream_t stream) {
    (void)in_sizes; (void)n_in; (void)out_size; (void)ws_size;
    const float* pos     = (const float*)d_in[0];
    const float* emb     = (const float*)d_in[1];
    const float* mlp_w1  = (const float*)d_in[2];
    const float* mlp_b1  = (const float*)d_in[3];
    const float* mlp_w2  = (const float*)d_in[4];
    const float* mlp_b2  = (const float*)d_in[5];
    const float* cf1     = (const float*)d_in[6];
    const float* cf2w    = (const float*)d_in[7];
    const float* cf2b    = (const float*)d_in[8];
    const float* intw    = (const float*)d_in[9];
    const float* intb    = (const float*)d_in[10];
    const float* ow1     = (const float*)d_in[11];
    const float* ob1     = (const float*)d_in[12];
    const float* ow2     = (const float*)d_in[13];
    const float* ob2     = (const float*)d_in[14];
    const int*   z       = (const int*)d_in[15];
    const int*   comp_id = (const int*)d_in[16];
    const int*   ei      = (const int*)d_in[17];
    const int*   comps_z = (const int*)d_in[18];
    float* out = (float*)d_out;

    char* ws = (char*)d_ws;
    size_t off = 0;
    auto alloc = [&](size_t bytes) -> void* {
        void* p = ws + off;
        off += (bytes + 255) & ~(size_t)255;
        return p;
    };
    // zeroed prefix: comp_acc | counts | types_acc | cursor | c_s | zsrc_s | ew_s
    float* comp_acc  = (float*)alloc((size_t)LL * NC * FD * 4);
    int*   counts    = (int*)  alloc(NC * 4);
    float* types_acc = (float*)alloc((size_t)NC * HD * 4);
    int*   cursor    = (int*)  alloc(NC * CSTR * 4);
    float* c_s       = (float*)alloc((size_t)PADE * 4);
    int*   zsrc_s    = (int*)  alloc((size_t)PADE * 4);
    float* ew_s      = (float*)alloc((size_t)PADE * 4);   // zeroed: dummy rows exact-0
    size_t zero_bytes = off;
    _Float16* xh16 = (_Float16*)alloc((size_t)LL * NZ * FD * 2);
    _Float16* tab  = (_Float16*)alloc((size_t)LL * NK * FD * 2);

    (void)hipMemsetAsync(d_ws, 0, zero_bytes, stream);

    setup_kernel<<<NSCATB + NXHZB + NTABB, 256, 0, stream>>>(
        pos, ei, comp_id, z, mlp_w1, mlp_b1, mlp_w2, mlp_b2, emb, cf1,
        counts, cursor, ew_s, c_s, zsrc_s, xh16, tab);
    edge_kernel <<<PADG, 256, 0, stream>>>(ew_s, c_s, zsrc_s, tab, xh16, comp_acc);
    comp_kernel <<<dim3(NC, LL), 128, 0, stream>>>(comp_acc, counts, cf2w, cf2b,
                                                   intw, intb, types_acc);
    readout_kernel<<<NGRAPH, 64, 0, stream>>>(types_acc, emb, comps_z,
                                              ow1, ob1, ow2, ob2, out);
}